// Round 4
// baseline (681.923 us; speedup 1.0000x reference)
//
#include <hip/hip_runtime.h>
#include <cstdint>

#define AS1 __attribute__((address_space(1)))
#define AS3 __attribute__((address_space(3)))

// Problem constants (fixed by setup_inputs)
constexpr int B  = 4;
constexpr int C  = 32;
constexpr int H  = 512;
constexpr int Wd = 960;
constexpr int Ht = H / 4;    // 128
constexpr int Wt = Wd / 4;   // 240
constexpr int HW = H * Wd;

constexpr int BLKX  = 256;        // x-pixels per block
constexpr int XMARG = 56;         // disp < 48+1+slant -> taps >= x-55
constexpr int SELEM = BLKX + 64;  // 320 staged floats per channel
// LDS = 320*32*4 = 40960 B -> 4 blocks/CU -> 16 waves/CU

__global__ __launch_bounds__(256, 4) void tile_warping_kernel(
    const float* __restrict__ tp,   // [B,3,Ht,Wt]
    const float* __restrict__ fl,   // [B,C,H,W]
    const float* __restrict__ fr,   // [B,C,H,W]
    float* __restrict__ out)        // [B,48,Ht,Wt]
{
    __shared__ float sm[SELEM * C];   // 40960 B

    const int lane = threadIdx.x;
    const int x0 = blockIdx.x * BLKX;
    const int y  = blockIdx.y;
    const int b  = blockIdx.z;
    const int xstart = x0 - XMARG;

    const int x = x0 + lane;
    const bool active = (x < Wd);
    const int xc = min(x, Wd - 1);        // clamped for safe loads on tail lanes

    // ---- 1) one burst: async-stage all 32 fea_r channel-rows into LDS ----
    const float* frrow = fr + ((size_t)b * C * H + y) * Wd;
    #pragma unroll
    for (int chunk = 0; chunk < (SELEM * C) / (BLKX * 4); ++chunk) {   // 10
        int e   = chunk * (BLKX * 4) + lane * 4;   // element index in sm
        int ch  = e / SELEM;
        int off = e - ch * SELEM;
        int gx  = min(max(xstart + off, 0), Wd - 4);  // clamped slots never read meaningfully
        const float* gp = frrow + (size_t)ch * HW + gx;
        __builtin_amdgcn_global_load_lds((const AS1 float*)gp,
                                         (AS3 float*)(&sm[e]), 16, 0, 0);
    }

    // ---- 2) same burst: prefetch all 32 fea_l values into registers ----
    // 32 independent loads in flight per thread; the barrier's vmcnt(0)
    // drains them together with the LDS-DMA (one merged latency event).
    const float* flp = fl + ((size_t)b * C * H + y) * Wd + xc;
    float lv[C];
    #pragma unroll
    for (int c = 0; c < C; ++c) lv[c] = flp[(size_t)c * HW];

    // ---- 3) per-thread disparity math (k=1 anchor; k=0/2 are integer shifts) ----
    const int ht = y >> 2, ii = y & 3;
    const int wt = xc >> 2, jj = xc & 3;
    const int tbase = ((b * 3) * Ht + ht) * Wt + wt;
    const float dv  = tp[tbase];
    const float dxv = tp[tbase + Ht * Wt];
    const float dyv = tp[tbase + 2 * Ht * Wt];
    const float oi = (float)ii - 1.5f;
    const float oj = (float)jj - 1.5f;
    // Reference rounding order for disp_d=0: ((d + 0) + oi*dy) + oj*dx
    float disp = ((dv + 0.0f) + oi * dyv) + oj * dxv;
    float xs = (float)xc - disp;          // xs for k=1
    float ff = floorf(xs);
    const float w  = xs - ff;
    const float w1 = 1.0f - w;
    const int   om1 = (int)ff - 1 - xstart;   // tap F-1; always within [0, SELEM-4]
    // xs_0 = xs+1 (disp_d=-1), xs_2 = xs-1 (disp_d=+1)
    const bool val0 = (xs >= -1.0f) && (xs <= 958.0f);
    const bool val1 = (xs >=  0.0f) && (xs <= 959.0f);
    const bool val2 = (xs >=  1.0f) && (xs <= 960.0f);

    __syncthreads();   // one merged drain: LDS-DMA + fea_l prefetch

    // ---- 4) stall-free compute: registers + LDS only ----
    float s0 = 0.f, s1 = 0.f, s2 = 0.f;
    #pragma unroll
    for (int c = 0; c < C; ++c) {
        float l = lv[c];
        const float* bp = sm + c * SELEM + om1;
        float t0 = bp[0];   // fr[F-1]
        float t1 = bp[1];   // fr[F]
        float t2 = bp[2];   // fr[F+1]
        float t3 = bp[3];   // fr[F+2]
        // k=0: taps (F+1, F+2); k=1: (F, F+1); k=2: (F-1, F)
        float wv0 = val0 ? (t2 * w1 + t3 * w) : 0.f;
        float wv1 = val1 ? (t1 * w1 + t2 * w) : 0.f;
        float wv2 = val2 ? (t0 * w1 + t1 * w) : 0.f;
        s0 += fabsf(l - wv0);
        s1 += fabsf(l - wv1);
        s2 += fabsf(l - wv2);
    }

    // ---- 5) store ----
    if (active) {
        const int obase = ((b * 48) * Ht + ht) * Wt + wt;
        out[obase + (0 * 16 + ii * 4 + jj) * (Ht * Wt)] = s0;
        out[obase + (1 * 16 + ii * 4 + jj) * (Ht * Wt)] = s1;
        out[obase + (2 * 16 + ii * 4 + jj) * (Ht * Wt)] = s2;
    }
}

extern "C" void kernel_launch(void* const* d_in, const int* in_sizes, int n_in,
                              void* d_out, int out_size, void* d_ws, size_t ws_size,
                              hipStream_t stream) {
    const float* tp = (const float*)d_in[0];
    const float* fl = (const float*)d_in[1];
    const float* fr = (const float*)d_in[2];
    float* out = (float*)d_out;

    dim3 grid((Wd + BLKX - 1) / BLKX, H, B);   // (4, 512, 4)
    tile_warping_kernel<<<grid, 256, 0, stream>>>(tp, fl, fr, out);
}